// Round 5
// baseline (434.177 us; speedup 1.0000x reference)
//
#include <hip/hip_runtime.h>
#include <hip/hip_bf16.h>

// ---------------- problem constants ----------------
constexpr int BATCH = 64;
constexpr int H1 = 126, W1 = 126, C1 = 16;   // conv1 out
constexpr int H2 = 124, W2 = 124, C2 = 32;   // conv2 out
constexpr int H3 = 122, W3 = 122, C3 = 40;   // conv3 out (x)
constexpr int HW3 = H3 * W3;                 // 14884

typedef __attribute__((ext_vector_type(8))) short bf16x8;
typedef __attribute__((ext_vector_type(4))) float f32x4;
typedef __attribute__((ext_vector_type(2))) float f32x2;

__device__ __forceinline__ ushort f2bf(float f) {
    __hip_bfloat16 h = __float2bfloat16(f);
    return *reinterpret_cast<ushort*>(&h);
}
__device__ __forceinline__ float bf2f(ushort u) {
    return __uint_as_float((unsigned)u << 16);
}

// ---------------- ws layout (bytes) ----------------
constexpr size_t IMGN_B  = 0;                                    // bf16 NHWC8 (64,128,128,8)
constexpr size_t IMGN_SZ = (size_t)BATCH * 128 * 128 * 8 * 2;
constexpr size_t A1_B    = (IMGN_B + IMGN_SZ + 255) & ~(size_t)255;   // bf16 NHWC (64,126,126,16)
constexpr size_t A1_SZB  = (size_t)BATCH * H1 * W1 * C1 * 2;
constexpr size_t A2_B    = (A1_B + A1_SZB + 255) & ~(size_t)255;      // bf16 NHWC (64,124,124,32)
constexpr size_t A2_SZB  = (size_t)BATCH * H2 * W2 * C2 * 2;
constexpr size_t BT1_B   = (A2_B + A2_SZB + 255) & ~(size_t)255;      // bf16 [16][96]
constexpr size_t BT2_B   = (BT1_B + 16 * 96 * 2 + 255) & ~(size_t)255;   // bf16 [32][160]
constexpr size_t BT3_B   = (BT2_B + 32 * 160 * 2 + 255) & ~(size_t)255;  // bf16 [48][288]
constexpr size_t QKW_B   = (BT3_B + 48 * 288 * 2 + 255) & ~(size_t)255;  // f32 [160]
constexpr size_t SMAT_B  = (QKW_B + 160 * 4 + 255) & ~(size_t)255;       // f32 [64][4][40]

// out layout (float elements)
constexpr size_t X_SZ     = (size_t)BATCH * C3 * HW3;
constexpr size_t PT_OFF   = X_SZ;
constexpr size_t FEAT_OFF = PT_OFF + BATCH * 8;
constexpr size_t ATT_OFF  = FEAT_OFF + BATCH * 40;

// ---------------- fold query into k_w; scale 1/122 ----------------
__global__ void k_qkw(const float* __restrict__ query, const float* __restrict__ k_w,
                      float* __restrict__ qkw) {
    int t = threadIdx.x;
    if (t < 160) {
        int q = t / 40, c = t % 40;
        float s = 0.f;
        #pragma unroll
        for (int d = 0; d < 10; ++d)
            s = fmaf(query[q * 10 + d], k_w[(d * 4 + q) * 40 + c], s);
        qkw[t] = s * (1.0f / 122.0f);
    }
}

// ---------------- weight transforms: Bt[n][k] bf16, zero-padded ----------------
__global__ void k_bt(const float* __restrict__ w1, ushort* __restrict__ bt1,
                     const float* __restrict__ w2, ushort* __restrict__ bt2,
                     const float* __restrict__ w3, ushort* __restrict__ bt3) {
    int t = blockIdx.x * 256 + threadIdx.x;
    if (t < 16 * 96) {                        // bt1: k = cell*8 + c (8-ch slots)
        int oc = t / 96, k = t % 96, cell = k >> 3, c = k & 7;
        float v = (c < 5 && cell < 9) ? w1[(oc * 5 + c) * 9 + cell] : 0.f;
        bt1[t] = f2bf(v);
    } else if (t < 16 * 96 + 32 * 160) {      // bt2: k = cell*16 + c, K=144 pad 160
        int u = t - 16 * 96;
        int n = u / 160, k = u % 160;
        float v = 0.f;
        if (k < 144) { int c = k & 15, cell = k >> 4; v = w2[(n * 16 + c) * 9 + cell]; }
        bt2[u] = f2bf(v);
    } else {
        int u = t - 16 * 96 - 32 * 160;       // bt3: k = cell*32 + c, N pad 40->48
        if (u < 48 * 288) {
            int n = u / 288, k = u % 288;
            float v = 0.f;
            if (n < 40) { int c = k & 31, cell = k >> 5; v = w3[(n * 32 + c) * 9 + cell]; }
            bt3[u] = f2bf(v);
        }
    }
}

// ---------------- pack img + coords into NHWC8 bf16 ----------------
__global__ __launch_bounds__(256) void k_imgN(const float* __restrict__ img,
                                              ushort* __restrict__ imgN) {
    int tid = blockIdx.x * 256 + threadIdx.x;     // 64*128*128 threads
    int b = tid >> 14, pix = tid & 16383;
    int y = pix >> 7, xc = pix & 127;
    const float* ip = img + (size_t)b * 3 * 16384 + pix;
    bf16x8 v;
    v[0] = (short)f2bf(ip[0]);
    v[1] = (short)f2bf(ip[16384]);
    v[2] = (short)f2bf(ip[32768]);
    v[3] = (short)f2bf(-1.0f + (2.0f / 127.0f) * (float)y);   // xx along H
    v[4] = (short)f2bf(-1.0f + (2.0f / 127.0f) * (float)xc);  // yy along W
    v[5] = 0; v[6] = 0; v[7] = 0;
    *(bf16x8*)(imgN + (size_t)tid * 8) = v;
}

// ---------------- conv1: implicit GEMM MFMA, 2 rows/block ----------------
// M=256 (2 rows x 128), N=16, K=96 (12 cell-slots, 9 valid)
__global__ __launch_bounds__(256) void k_conv1_mfma(const ushort* __restrict__ imgN,
                                                    const ushort* __restrict__ bt1,
                                                    const float* __restrict__ b1,
                                                    ushort* __restrict__ a1) {
    __shared__ ushort sx1[256][16];
    const int b = blockIdx.y, y0 = blockIdx.x * 2;
    const int t = threadIdx.x, lane = t & 63, w = t >> 6;
    const int col = lane & 15, g = lane >> 4;
    const int ro = w >> 1, xbase = (w & 1) * 64;

    f32x4 acc[4];
    const float bv = b1[col];
    #pragma unroll
    for (int mi = 0; mi < 4; ++mi) acc[mi] = (f32x4){bv, bv, bv, bv};

    #pragma unroll
    for (int ks = 0; ks < 3; ++ks) {
        bf16x8 bf = *(const bf16x8*)(bt1 + (size_t)col * 96 + ks * 32 + 8 * g);
        const int cell = ks * 4 + g;
        const bool valid = (cell < 9);
        const int ky = cell / 3, kx = cell % 3;
        #pragma unroll
        for (int mi = 0; mi < 4; ++mi) {
            const int xcol = xbase + mi * 16 + col;
            bf16x8 af = (bf16x8)0;
            if (valid) {
                const int row = y0 + ro + ky;
                const int xin = min(xcol + kx, 127);
                af = *(const bf16x8*)(imgN + (((size_t)b * 128 + row) * 128 + xin) * 8);
            }
            acc[mi] = __builtin_amdgcn_mfma_f32_16x16x32_bf16(af, bf, acc[mi], 0, 0, 0);
        }
    }

    #pragma unroll
    for (int mi = 0; mi < 4; ++mi) {
        const int m0 = w * 64 + mi * 16 + 4 * g;
        #pragma unroll
        for (int r = 0; r < 4; ++r)
            sx1[m0 + r][col] = f2bf(fmaxf(acc[mi][r], 0.0f));
    }
    __syncthreads();

    // write rows y0, y0+1: 2 x 126 x 16 ch = 504 ushort8 chunks
    ushort* op = a1 + ((size_t)b * H1 + y0) * W1 * C1;
    for (int i = t; i < 504; i += 256) {
        int ro2 = i / 252, r = i % 252, xcol = r >> 1, c0 = (r & 1) * 8;
        *(bf16x8*)(op + ((size_t)ro2 * W1 + xcol) * C1 + c0) =
            *(const bf16x8*)(&sx1[ro2 * 128 + xcol][c0]);
    }
}

// ---------------- conv2: implicit GEMM MFMA, 2 rows/block ----------------
// M=256, N=32, K=144 pad 160
__global__ __launch_bounds__(256) void k_conv2_mfma(const ushort* __restrict__ a1,
                                                    const ushort* __restrict__ bt2,
                                                    const float* __restrict__ b2,
                                                    ushort* __restrict__ a2) {
    __shared__ ushort sx2[256][40];   // stride 40 keeps 16B chunks aligned
    const int b = blockIdx.y, y0 = blockIdx.x * 2;
    const int t = threadIdx.x, lane = t & 63, w = t >> 6;
    const int col = lane & 15, g = lane >> 4;
    const int ro = w >> 1, xbase = (w & 1) * 64;

    f32x4 acc[4][2];
    #pragma unroll
    for (int mi = 0; mi < 4; ++mi)
        #pragma unroll
        for (int nf = 0; nf < 2; ++nf) {
            float bv = b2[nf * 16 + col];
            acc[mi][nf] = (f32x4){bv, bv, bv, bv};
        }

    #pragma unroll
    for (int ks = 0; ks < 5; ++ks) {
        bf16x8 bf[2];
        #pragma unroll
        for (int nf = 0; nf < 2; ++nf)
            bf[nf] = *(const bf16x8*)(bt2 + (size_t)(nf * 16 + col) * 160 + ks * 32 + 8 * g);
        const int cell = 2 * ks + (g >> 1);
        const bool valid = (cell <= 8);
        const int ky = cell / 3, kx = cell - ky * 3;
        const int c0 = 8 * (g & 1);
        #pragma unroll
        for (int mi = 0; mi < 4; ++mi) {
            const int xcol = xbase + mi * 16 + col;
            bf16x8 af = (bf16x8)0;
            if (valid) {
                const int row = y0 + ro + ky;
                const int xin = min(xcol + kx, W1 - 1);
                af = *(const bf16x8*)(a1 + (((size_t)b * H1 + row) * W1 + xin) * C1 + c0);
            }
            #pragma unroll
            for (int nf = 0; nf < 2; ++nf)
                acc[mi][nf] = __builtin_amdgcn_mfma_f32_16x16x32_bf16(af, bf[nf], acc[mi][nf], 0, 0, 0);
        }
    }

    #pragma unroll
    for (int mi = 0; mi < 4; ++mi) {
        const int m0 = w * 64 + mi * 16 + 4 * g;
        #pragma unroll
        for (int nf = 0; nf < 2; ++nf)
            #pragma unroll
            for (int r = 0; r < 4; ++r)
                sx2[m0 + r][nf * 16 + col] = f2bf(fmaxf(acc[mi][nf][r], 0.0f));
    }
    __syncthreads();

    // write rows y0, y0+1: 2 x 124 x 32 ch = 992 ushort8 chunks
    ushort* op = a2 + ((size_t)b * H2 + y0) * W2 * C2;
    for (int i = t; i < 992; i += 256) {
        int ro2 = i / 496, r = i % 496, xcol = r >> 2, c0 = (r & 3) * 8;
        *(bf16x8*)(op + ((size_t)ro2 * W2 + xcol) * C2 + c0) =
            *(const bf16x8*)(&sx2[ro2 * 128 + xcol][c0]);
    }
}

// ---------------- conv3: implicit GEMM MFMA + fused scores, 2 rows/block ----------------
// M=256, N=40 pad 48, K=288. x stored DIRECTLY from regs (8B float2, alignment-safe);
// bf16 LDS copy only for the score dot (22.5KB -> 6 blocks/CU).
__global__ __launch_bounds__(256) void k_conv3_mfma(const ushort* __restrict__ a2,
                                                    const ushort* __restrict__ bt3,
                                                    const float* __restrict__ b3,
                                                    const float* __restrict__ qkw,
                                                    float* __restrict__ x,
                                                    float* __restrict__ att) {
    __shared__ ushort sxb[256][44];
    __shared__ float lq[160];
    const int b = blockIdx.y, y0 = blockIdx.x * 2;
    const int t = threadIdx.x, lane = t & 63, w = t >> 6;
    const int col = lane & 15, g = lane >> 4;
    const int ro = w >> 1, xbase = (w & 1) * 64;

    f32x4 acc[4][3];
    #pragma unroll
    for (int mi = 0; mi < 4; ++mi)
        #pragma unroll
        for (int nf = 0; nf < 3; ++nf) {
            const int ch = nf * 16 + col;
            float bv = (ch < 40) ? b3[ch] : 0.f;
            acc[mi][nf] = (f32x4){bv, bv, bv, bv};
        }

    #pragma unroll
    for (int ky = 0; ky < 3; ++ky) {
        #pragma unroll
        for (int kx = 0; kx < 3; ++kx) {
            const int ks = ky * 3 + kx;
            bf16x8 bf[3];
            #pragma unroll
            for (int nf = 0; nf < 3; ++nf)
                bf[nf] = *(const bf16x8*)(bt3 + (size_t)(nf * 16 + col) * 288 + ks * 32 + 8 * g);
            const ushort* arow = a2 + ((size_t)b * H2 + (y0 + ro + ky)) * W2 * C2;
            #pragma unroll
            for (int mi = 0; mi < 4; ++mi) {
                const int xcol = xbase + mi * 16 + col;
                const int xin = min(xcol + kx, W2 - 1);
                bf16x8 af = *(const bf16x8*)(arow + (size_t)xin * C2 + 8 * g);
                #pragma unroll
                for (int nf = 0; nf < 3; ++nf)
                    acc[mi][nf] = __builtin_amdgcn_mfma_f32_16x16x32_bf16(af, bf[nf], acc[mi][nf], 0, 0, 0);
            }
        }
    }

    for (int i = t; i < 160; i += 256) lq[i] = qkw[i];

    // ReLU, direct x stores (NCHW: 4 consecutive positions per channel), bf16 LDS stage
    #pragma unroll
    for (int mi = 0; mi < 4; ++mi) {
        const int m0 = w * 64 + mi * 16 + 4 * g;
        const int ro2 = m0 >> 7, xc0 = m0 & 127;
        const int row = y0 + ro2;
        #pragma unroll
        for (int nf = 0; nf < 3; ++nf) {
            const int ch = nf * 16 + col;
            if (ch < 40) {
                f32x4 v;
                #pragma unroll
                for (int r = 0; r < 4; ++r) v[r] = fmaxf(acc[mi][nf][r], 0.0f);
                // LDS (bf16) for score epilogue
                #pragma unroll
                for (int r = 0; r < 4; ++r) sxb[m0 + r][ch] = f2bf(v[r]);
                // direct global store: 8B-aligned float2 pairs
                if (xc0 < 120) {
                    float* xp = x + ((size_t)b * C3 + ch) * HW3 + (size_t)row * W3 + xc0;
                    *(f32x2*)xp       = (f32x2){v[0], v[1]};
                    *(f32x2*)(xp + 2) = (f32x2){v[2], v[3]};
                } else if (xc0 == 120) {
                    float* xp = x + ((size_t)b * C3 + ch) * HW3 + (size_t)row * W3 + xc0;
                    *(f32x2*)xp = (f32x2){v[0], v[1]};
                }
            }
        }
    }
    __syncthreads();

    // score epilogue: 244 positions (2 rows x 122)
    if (t < 244) {
        const int ro2 = (t >= 122) ? 1 : 0;
        const int xcol = t - ro2 * 122;
        const int srow = ro2 * 128 + xcol;
        const ushort* rowp = &sxb[srow][0];
        float s0 = 0, s1 = 0, s2 = 0, s3 = 0;
        #pragma unroll
        for (int k = 0; k < 10; ++k) {
            uint2 u = *(const uint2*)(rowp + 4 * k);
            float v0 = bf2f((ushort)(u.x & 0xffff));
            float v1 = bf2f((ushort)(u.x >> 16));
            float v2 = bf2f((ushort)(u.y & 0xffff));
            float v3 = bf2f((ushort)(u.y >> 16));
            const int c = 4 * k;
            s0 = fmaf(v0, lq[c], fmaf(v1, lq[c + 1], fmaf(v2, lq[c + 2], fmaf(v3, lq[c + 3], s0))));
            s1 = fmaf(v0, lq[40 + c], fmaf(v1, lq[41 + c], fmaf(v2, lq[42 + c], fmaf(v3, lq[43 + c], s1))));
            s2 = fmaf(v0, lq[80 + c], fmaf(v1, lq[81 + c], fmaf(v2, lq[82 + c], fmaf(v3, lq[83 + c], s2))));
            s3 = fmaf(v0, lq[120 + c], fmaf(v1, lq[121 + c], fmaf(v2, lq[122 + c], fmaf(v3, lq[123 + c], s3))));
        }
        const int p = (y0 + ro2) * W3 + xcol;
        float* ap = att + (size_t)b * 4 * HW3 + p;
        ap[0] = s0; ap[HW3] = s1; ap[2 * HW3] = s2; ap[3 * HW3] = s3;
    }
}

// ---------------- block reduction helpers ----------------
__device__ __forceinline__ float block_max(float v, float* sred) {
    #pragma unroll
    for (int off = 32; off >= 1; off >>= 1) v = fmaxf(v, __shfl_xor(v, off));
    if ((threadIdx.x & 63) == 0) sred[threadIdx.x >> 6] = v;
    __syncthreads();
    float r = fmaxf(fmaxf(sred[0], sred[1]), fmaxf(sred[2], sred[3]));
    __syncthreads();
    return r;
}
__device__ __forceinline__ float block_sum(float v, float* sred) {
    #pragma unroll
    for (int off = 32; off >= 1; off >>= 1) v += __shfl_xor(v, off);
    if ((threadIdx.x & 63) == 0) sred[threadIdx.x >> 6] = v;
    __syncthreads();
    float r = sred[0] + sred[1] + sred[2] + sred[3];
    __syncthreads();
    return r;
}

// ---------------- softmax (online max+sum single read pass), fuses pt_out ----------------
__global__ __launch_bounds__(256) void k_softmax(float* __restrict__ att,
                                                 float* __restrict__ pt_out) {
    __shared__ float sred[4];
    const int bq = blockIdx.x;
    float* row = att + (size_t)bq * HW3;
    const int t = threadIdx.x;

    float m_t = -1e30f, s_t = 0.f;
    for (int p = t; p < HW3; p += 256) {
        float v = row[p];
        if (v <= m_t) {
            s_t += __expf(v - m_t);
        } else {
            s_t = s_t * __expf(m_t - v) + 1.0f;
            m_t = v;
        }
    }
    float M = block_max(m_t, sred);
    s_t *= __expf(m_t - M);
    float S = block_sum(s_t, sred);
    const float inv = 1.0f / S;

    float sx = 0.f, sy = 0.f;
    for (int p = t; p < HW3; p += 256) {
        float wgt = __expf(row[p] - M) * inv;
        row[p] = wgt;
        int pr = p / W3, pc = p % W3;
        sx = fmaf(wgt, (float)pc * (1.0f / (W3 - 1)), sx);
        sy = fmaf(wgt, (float)pr * (1.0f / (H3 - 1)), sy);
    }
    sx = block_sum(sx, sred);
    sy = block_sum(sy, sred);
    if (t == 0) { pt_out[bq * 2] = sx; pt_out[bq * 2 + 1] = sy; }
}

// ---------------- smat: chunked, x and att read ONCE, atomic accumulate ----------------
// grid (16 chunks, B), 320 threads = 40 ch x 8 p-lanes
constexpr int SM_CHUNKS = 16;
constexpr int SM_CHUNK  = (HW3 + SM_CHUNKS - 1) / SM_CHUNKS;   // 931
__global__ __launch_bounds__(320) void k_smat(const float* __restrict__ x,
                                              const float* __restrict__ att,
                                              float* __restrict__ smat) {
    const int chunk = blockIdx.x, b = blockIdx.y;
    const int t = threadIdx.x;
    const int c = t >> 3, pl = t & 7;
    const int p0 = chunk * SM_CHUNK;
    const int pend = min(p0 + SM_CHUNK, HW3);
    const float* xp = x + ((size_t)b * C3 + c) * HW3;
    const float* ap = att + (size_t)b * 4 * HW3;
    float a0 = 0, a1 = 0, a2 = 0, a3 = 0;
    for (int p = p0 + pl; p < pend; p += 8) {
        float v = xp[p];
        a0 = fmaf(v, ap[p], a0);
        a1 = fmaf(v, ap[HW3 + p], a1);
        a2 = fmaf(v, ap[2 * HW3 + p], a2);
        a3 = fmaf(v, ap[3 * HW3 + p], a3);
    }
    #pragma unroll
    for (int off = 4; off >= 1; off >>= 1) {
        a0 += __shfl_xor(a0, off);
        a1 += __shfl_xor(a1, off);
        a2 += __shfl_xor(a2, off);
        a3 += __shfl_xor(a3, off);
    }
    if (pl == 0) {
        atomicAdd(&smat[((size_t)b * 4 + 0) * 40 + c], a0);
        atomicAdd(&smat[((size_t)b * 4 + 1) * 40 + c], a1);
        atomicAdd(&smat[((size_t)b * 4 + 2) * 40 + c], a2);
        atomicAdd(&smat[((size_t)b * 4 + 3) * 40 + c], a3);
    }
}

// ---------------- feat_out ----------------
__global__ void k_feat(const float* __restrict__ smat, const float* __restrict__ f_w,
                       float* __restrict__ feat) {
    const int b = blockIdx.x, t = threadIdx.x;
    if (t < 40) {
        int q = t / 10, d = t % 10;
        float s = 0.f;
        #pragma unroll
        for (int c = 0; c < 40; ++c)
            s = fmaf(f_w[(d * 4 + q) * 40 + c], smat[((size_t)b * 4 + q) * 40 + c], s);
        feat[b * 40 + t] = s;
    }
}

// ---------------- launch ----------------
extern "C" void kernel_launch(void* const* d_in, const int* in_sizes, int n_in,
                              void* d_out, int out_size, void* d_ws, size_t ws_size,
                              hipStream_t stream) {
    const float* img   = (const float*)d_in[0];
    const float* w1    = (const float*)d_in[1];
    const float* b1    = (const float*)d_in[2];
    const float* w2    = (const float*)d_in[3];
    const float* b2    = (const float*)d_in[4];
    const float* w3    = (const float*)d_in[5];
    const float* b3    = (const float*)d_in[6];
    const float* k_w   = (const float*)d_in[7];
    const float* f_w   = (const float*)d_in[8];
    const float* query = (const float*)d_in[9];

    char* ws = (char*)d_ws;
    ushort* imgN = (ushort*)(ws + IMGN_B);
    ushort* a1   = (ushort*)(ws + A1_B);
    ushort* a2   = (ushort*)(ws + A2_B);
    ushort* bt1  = (ushort*)(ws + BT1_B);
    ushort* bt2  = (ushort*)(ws + BT2_B);
    ushort* bt3  = (ushort*)(ws + BT3_B);
    float*  qkw  = (float*)(ws + QKW_B);
    float*  smat = (float*)(ws + SMAT_B);

    float* out  = (float*)d_out;
    float* x    = out;
    float* pt   = out + PT_OFF;
    float* feat = out + FEAT_OFF;
    float* att  = out + ATT_OFF;

    hipMemsetAsync(smat, 0, (size_t)BATCH * 4 * 40 * sizeof(float), stream);
    k_qkw<<<1, 256, 0, stream>>>(query, k_w, qkw);
    k_bt<<<80, 256, 0, stream>>>(w1, bt1, w2, bt2, w3, bt3);
    k_imgN<<<(BATCH * 16384) / 256, 256, 0, stream>>>(img, imgN);
    k_conv1_mfma<<<dim3(63, BATCH), 256, 0, stream>>>(imgN, bt1, b1, a1);
    k_conv2_mfma<<<dim3(62, BATCH), 256, 0, stream>>>(a1, bt2, b2, a2);
    k_conv3_mfma<<<dim3(61, BATCH), 256, 0, stream>>>(a2, bt3, b3, qkw, x, att);
    k_softmax<<<BATCH * 4, 256, 0, stream>>>(att, pt);
    k_smat<<<dim3(SM_CHUNKS, BATCH), 320, 0, stream>>>(x, att, smat);
    k_feat<<<BATCH, 64, 0, stream>>>(smat, f_w, feat);
}

// Round 6
// 412.541 us; speedup vs baseline: 1.0524x; 1.0524x over previous
//
#include <hip/hip_runtime.h>
#include <hip/hip_bf16.h>

// ---------------- problem constants ----------------
constexpr int BATCH = 64;
constexpr int H1 = 126, W1 = 126, C1 = 16;   // conv1 out
constexpr int H2 = 124, W2 = 124, C2 = 32;   // conv2 out
constexpr int H3 = 122, W3 = 122, C3 = 40;   // conv3 out (x)
constexpr int HW3 = H3 * W3;                 // 14884

typedef __attribute__((ext_vector_type(8))) short bf16x8;
typedef __attribute__((ext_vector_type(4))) float f32x4;
typedef __attribute__((ext_vector_type(2))) float f32x2;

__device__ __forceinline__ ushort f2bf(float f) {
    __hip_bfloat16 h = __float2bfloat16(f);
    return *reinterpret_cast<ushort*>(&h);
}
__device__ __forceinline__ float bf2f(ushort u) {
    return __uint_as_float((unsigned)u << 16);
}

// ---------------- ws layout (bytes) ----------------
constexpr size_t IMGN_B  = 0;                                    // bf16 NHWC8 (64,128,128,8)
constexpr size_t IMGN_SZ = (size_t)BATCH * 128 * 128 * 8 * 2;
constexpr size_t A1_B    = (IMGN_B + IMGN_SZ + 255) & ~(size_t)255;   // bf16 NHWC (64,126,126,16)
constexpr size_t A1_SZB  = (size_t)BATCH * H1 * W1 * C1 * 2;
constexpr size_t A2_B    = (A1_B + A1_SZB + 255) & ~(size_t)255;      // bf16 NHWC (64,124,124,32)
constexpr size_t A2_SZB  = (size_t)BATCH * H2 * W2 * C2 * 2;
constexpr size_t BT1_B   = (A2_B + A2_SZB + 255) & ~(size_t)255;      // bf16 [16][96]
constexpr size_t BT2_B   = (BT1_B + 16 * 96 * 2 + 255) & ~(size_t)255;   // bf16 [32][160]
constexpr size_t BT3_B   = (BT2_B + 32 * 160 * 2 + 255) & ~(size_t)255;  // bf16 [48][288]
constexpr size_t QKW_B   = (BT3_B + 48 * 288 * 2 + 255) & ~(size_t)255;  // f32 [160]
// raw attention accumulators (memset to 0 each launch): smat_raw[64][4][40], S_raw[64][4], pt_raw[64][4][2]
constexpr size_t SMATR_B = (QKW_B + 160 * 4 + 255) & ~(size_t)255;
constexpr size_t SR_B    = SMATR_B + (size_t)BATCH * 160 * 4;
constexpr size_t PTR_B   = SR_B + (size_t)BATCH * 4 * 4;
constexpr size_t RAW_SZB = (size_t)BATCH * 160 * 4 + (size_t)BATCH * 4 * 4 + (size_t)BATCH * 8 * 4;
constexpr size_t INV_B   = (SMATR_B + RAW_SZB + 255) & ~(size_t)255;   // f32 [256]

// out layout (float elements)
constexpr size_t X_SZ     = (size_t)BATCH * C3 * HW3;
constexpr size_t PT_OFF   = X_SZ;
constexpr size_t FEAT_OFF = PT_OFF + BATCH * 8;
constexpr size_t ATT_OFF  = FEAT_OFF + BATCH * 40;

// ---------------- fold query into k_w; scale 1/122 ----------------
__global__ void k_qkw(const float* __restrict__ query, const float* __restrict__ k_w,
                      float* __restrict__ qkw) {
    int t = threadIdx.x;
    if (t < 160) {
        int q = t / 40, c = t % 40;
        float s = 0.f;
        #pragma unroll
        for (int d = 0; d < 10; ++d)
            s = fmaf(query[q * 10 + d], k_w[(d * 4 + q) * 40 + c], s);
        qkw[t] = s * (1.0f / 122.0f);
    }
}

// ---------------- weight transforms: Bt[n][k] bf16, zero-padded ----------------
__global__ void k_bt(const float* __restrict__ w1, ushort* __restrict__ bt1,
                     const float* __restrict__ w2, ushort* __restrict__ bt2,
                     const float* __restrict__ w3, ushort* __restrict__ bt3) {
    int t = blockIdx.x * 256 + threadIdx.x;
    if (t < 16 * 96) {                        // bt1: k = cell*8 + c (8-ch slots)
        int oc = t / 96, k = t % 96, cell = k >> 3, c = k & 7;
        float v = (c < 5 && cell < 9) ? w1[(oc * 5 + c) * 9 + cell] : 0.f;
        bt1[t] = f2bf(v);
    } else if (t < 16 * 96 + 32 * 160) {      // bt2: k = cell*16 + c, K=144 pad 160
        int u = t - 16 * 96;
        int n = u / 160, k = u % 160;
        float v = 0.f;
        if (k < 144) { int c = k & 15, cell = k >> 4; v = w2[(n * 16 + c) * 9 + cell]; }
        bt2[u] = f2bf(v);
    } else {
        int u = t - 16 * 96 - 32 * 160;       // bt3: k = cell*32 + c, N pad 40->48
        if (u < 48 * 288) {
            int n = u / 288, k = u % 288;
            float v = 0.f;
            if (n < 40) { int c = k & 31, cell = k >> 5; v = w3[(n * 32 + c) * 9 + cell]; }
            bt3[u] = f2bf(v);
        }
    }
}

// ---------------- pack img + coords into NHWC8 bf16 ----------------
__global__ __launch_bounds__(256) void k_imgN(const float* __restrict__ img,
                                              ushort* __restrict__ imgN) {
    int tid = blockIdx.x * 256 + threadIdx.x;     // 64*128*128 threads
    int b = tid >> 14, pix = tid & 16383;
    int y = pix >> 7, xc = pix & 127;
    const float* ip = img + (size_t)b * 3 * 16384 + pix;
    bf16x8 v;
    v[0] = (short)f2bf(ip[0]);
    v[1] = (short)f2bf(ip[16384]);
    v[2] = (short)f2bf(ip[32768]);
    v[3] = (short)f2bf(-1.0f + (2.0f / 127.0f) * (float)y);   // xx along H
    v[4] = (short)f2bf(-1.0f + (2.0f / 127.0f) * (float)xc);  // yy along W
    v[5] = 0; v[6] = 0; v[7] = 0;
    *(bf16x8*)(imgN + (size_t)tid * 8) = v;
}

// ---------------- conv1: implicit GEMM MFMA, 2 rows/block ----------------
__global__ __launch_bounds__(256) void k_conv1_mfma(const ushort* __restrict__ imgN,
                                                    const ushort* __restrict__ bt1,
                                                    const float* __restrict__ b1,
                                                    ushort* __restrict__ a1) {
    __shared__ ushort sx1[256][16];
    const int b = blockIdx.y, y0 = blockIdx.x * 2;
    const int t = threadIdx.x, lane = t & 63, w = t >> 6;
    const int col = lane & 15, g = lane >> 4;
    const int ro = w >> 1, xbase = (w & 1) * 64;

    f32x4 acc[4];
    const float bv = b1[col];
    #pragma unroll
    for (int mi = 0; mi < 4; ++mi) acc[mi] = (f32x4){bv, bv, bv, bv};

    #pragma unroll
    for (int ks = 0; ks < 3; ++ks) {
        bf16x8 bf = *(const bf16x8*)(bt1 + (size_t)col * 96 + ks * 32 + 8 * g);
        const int cell = ks * 4 + g;
        const bool valid = (cell < 9);
        const int ky = cell / 3, kx = cell % 3;
        #pragma unroll
        for (int mi = 0; mi < 4; ++mi) {
            const int xcol = xbase + mi * 16 + col;
            bf16x8 af = (bf16x8)0;
            if (valid) {
                const int row = y0 + ro + ky;
                const int xin = min(xcol + kx, 127);
                af = *(const bf16x8*)(imgN + (((size_t)b * 128 + row) * 128 + xin) * 8);
            }
            acc[mi] = __builtin_amdgcn_mfma_f32_16x16x32_bf16(af, bf, acc[mi], 0, 0, 0);
        }
    }

    #pragma unroll
    for (int mi = 0; mi < 4; ++mi) {
        const int m0 = w * 64 + mi * 16 + 4 * g;
        #pragma unroll
        for (int r = 0; r < 4; ++r)
            sx1[m0 + r][col] = f2bf(fmaxf(acc[mi][r], 0.0f));
    }
    __syncthreads();

    ushort* op = a1 + ((size_t)b * H1 + y0) * W1 * C1;
    for (int i = t; i < 504; i += 256) {
        int ro2 = i / 252, r = i % 252, xcol = r >> 1, c0 = (r & 1) * 8;
        *(bf16x8*)(op + ((size_t)ro2 * W1 + xcol) * C1 + c0) =
            *(const bf16x8*)(&sx1[ro2 * 128 + xcol][c0]);
    }
}

// ---------------- conv2: implicit GEMM MFMA, 2 rows/block ----------------
__global__ __launch_bounds__(256) void k_conv2_mfma(const ushort* __restrict__ a1,
                                                    const ushort* __restrict__ bt2,
                                                    const float* __restrict__ b2,
                                                    ushort* __restrict__ a2) {
    __shared__ ushort sx2[256][40];
    const int b = blockIdx.y, y0 = blockIdx.x * 2;
    const int t = threadIdx.x, lane = t & 63, w = t >> 6;
    const int col = lane & 15, g = lane >> 4;
    const int ro = w >> 1, xbase = (w & 1) * 64;

    f32x4 acc[4][2];
    #pragma unroll
    for (int mi = 0; mi < 4; ++mi)
        #pragma unroll
        for (int nf = 0; nf < 2; ++nf) {
            float bv = b2[nf * 16 + col];
            acc[mi][nf] = (f32x4){bv, bv, bv, bv};
        }

    #pragma unroll
    for (int ks = 0; ks < 5; ++ks) {
        bf16x8 bf[2];
        #pragma unroll
        for (int nf = 0; nf < 2; ++nf)
            bf[nf] = *(const bf16x8*)(bt2 + (size_t)(nf * 16 + col) * 160 + ks * 32 + 8 * g);
        const int cell = 2 * ks + (g >> 1);
        const bool valid = (cell <= 8);
        const int ky = cell / 3, kx = cell - ky * 3;
        const int c0 = 8 * (g & 1);
        #pragma unroll
        for (int mi = 0; mi < 4; ++mi) {
            const int xcol = xbase + mi * 16 + col;
            bf16x8 af = (bf16x8)0;
            if (valid) {
                const int row = y0 + ro + ky;
                const int xin = min(xcol + kx, W1 - 1);
                af = *(const bf16x8*)(a1 + (((size_t)b * H1 + row) * W1 + xin) * C1 + c0);
            }
            #pragma unroll
            for (int nf = 0; nf < 2; ++nf)
                acc[mi][nf] = __builtin_amdgcn_mfma_f32_16x16x32_bf16(af, bf[nf], acc[mi][nf], 0, 0, 0);
        }
    }

    #pragma unroll
    for (int mi = 0; mi < 4; ++mi) {
        const int m0 = w * 64 + mi * 16 + 4 * g;
        #pragma unroll
        for (int nf = 0; nf < 2; ++nf)
            #pragma unroll
            for (int r = 0; r < 4; ++r)
                sx2[m0 + r][nf * 16 + col] = f2bf(fmaxf(acc[mi][nf][r], 0.0f));
    }
    __syncthreads();

    ushort* op = a2 + ((size_t)b * H2 + y0) * W2 * C2;
    for (int i = t; i < 992; i += 256) {
        int ro2 = i / 496, r = i % 496, xcol = r >> 2, c0 = (r & 3) * 8;
        *(bf16x8*)(op + ((size_t)ro2 * W2 + xcol) * C2 + c0) =
            *(const bf16x8*)(&sx2[ro2 * 128 + xcol][c0]);
    }
}

// ---------------- conv3: implicit GEMM MFMA + fused scores/exp + fused attention
// reductions (no-max softmax: e=exp(s) accumulated raw; normalize later).
// Writes: x (coalesced from LDS, bf16-rounded), att_raw=e, atomic partials.
__global__ __launch_bounds__(256) void k_conv3_mfma(const ushort* __restrict__ a2,
                                                    const ushort* __restrict__ bt3,
                                                    const float* __restrict__ b3,
                                                    const float* __restrict__ qkw,
                                                    float* __restrict__ x,
                                                    float* __restrict__ att,
                                                    float* __restrict__ smat_raw,
                                                    float* __restrict__ S_raw,
                                                    float* __restrict__ pt_raw) {
    __shared__ ushort sxb[256][42];     // bf16 x tile, PAD=42
    __shared__ f32x4 se4[244];          // e per position (4 q)
    __shared__ float ls[6][4][40];      // smat partials
    __shared__ float lq[160];
    __shared__ float sr12[4][12];       // per-wave S/pt partials
    const int b = blockIdx.y, y0 = blockIdx.x * 2;
    const int t = threadIdx.x, lane = t & 63, w = t >> 6;
    const int col = lane & 15, g = lane >> 4;
    const int ro = w >> 1, xbase = (w & 1) * 64;

    f32x4 acc[4][3];
    #pragma unroll
    for (int mi = 0; mi < 4; ++mi)
        #pragma unroll
        for (int nf = 0; nf < 3; ++nf) {
            const int ch = nf * 16 + col;
            float bv = (ch < 40) ? b3[ch] : 0.f;
            acc[mi][nf] = (f32x4){bv, bv, bv, bv};
        }

    #pragma unroll
    for (int ky = 0; ky < 3; ++ky) {
        #pragma unroll
        for (int kx = 0; kx < 3; ++kx) {
            const int ks = ky * 3 + kx;
            bf16x8 bf[3];
            #pragma unroll
            for (int nf = 0; nf < 3; ++nf)
                bf[nf] = *(const bf16x8*)(bt3 + (size_t)(nf * 16 + col) * 288 + ks * 32 + 8 * g);
            const ushort* arow = a2 + ((size_t)b * H2 + (y0 + ro + ky)) * W2 * C2;
            #pragma unroll
            for (int mi = 0; mi < 4; ++mi) {
                const int xcol = xbase + mi * 16 + col;
                const int xin = min(xcol + kx, W2 - 1);
                bf16x8 af = *(const bf16x8*)(arow + (size_t)xin * C2 + 8 * g);
                #pragma unroll
                for (int nf = 0; nf < 3; ++nf)
                    acc[mi][nf] = __builtin_amdgcn_mfma_f32_16x16x32_bf16(af, bf[nf], acc[mi][nf], 0, 0, 0);
            }
        }
    }

    for (int i = t; i < 160; i += 256) lq[i] = qkw[i];
    #pragma unroll
    for (int mi = 0; mi < 4; ++mi) {
        const int m0 = w * 64 + mi * 16 + 4 * g;
        #pragma unroll
        for (int nf = 0; nf < 3; ++nf) {
            const int ch = nf * 16 + col;
            if (ch < 40) {
                #pragma unroll
                for (int r = 0; r < 4; ++r)
                    sxb[m0 + r][ch] = f2bf(fmaxf(acc[mi][nf][r], 0.0f));
            }
        }
    }
    __syncthreads();

    // ---- phase A: scores -> e = exp(s); write att_raw; stage e ----
    float e0 = 0, e1 = 0, e2 = 0, e3 = 0, pxv = 0, pyv = 0;
    if (t < 244) {
        const int ro2 = (t >= 122) ? 1 : 0;
        const int xcol = t - ro2 * 122;
        const int srow = ro2 * 128 + xcol;
        const ushort* rowp = &sxb[srow][0];
        float s0 = 0, s1 = 0, s2 = 0, s3 = 0;
        #pragma unroll
        for (int k = 0; k < 10; ++k) {
            uint ua = *(const uint*)(rowp + 4 * k);       // 4B-aligned (PAD=42)
            uint ub = *(const uint*)(rowp + 4 * k + 2);
            float v0 = bf2f((ushort)(ua & 0xffff));
            float v1 = bf2f((ushort)(ua >> 16));
            float v2 = bf2f((ushort)(ub & 0xffff));
            float v3 = bf2f((ushort)(ub >> 16));
            const int c = 4 * k;
            s0 = fmaf(v0, lq[c], fmaf(v1, lq[c + 1], fmaf(v2, lq[c + 2], fmaf(v3, lq[c + 3], s0))));
            s1 = fmaf(v0, lq[40 + c], fmaf(v1, lq[41 + c], fmaf(v2, lq[42 + c], fmaf(v3, lq[43 + c], s1))));
            s2 = fmaf(v0, lq[80 + c], fmaf(v1, lq[81 + c], fmaf(v2, lq[82 + c], fmaf(v3, lq[83 + c], s2))));
            s3 = fmaf(v0, lq[120 + c], fmaf(v1, lq[121 + c], fmaf(v2, lq[122 + c], fmaf(v3, lq[123 + c], s3))));
        }
        e0 = __expf(s0); e1 = __expf(s1); e2 = __expf(s2); e3 = __expf(s3);
        const int p = (y0 + ro2) * W3 + xcol;
        float* ap = att + (size_t)b * 4 * HW3 + p;
        ap[0] = e0; ap[HW3] = e1; ap[2 * HW3] = e2; ap[3 * HW3] = e3;
        se4[t] = (f32x4){e0, e1, e2, e3};
        pxv = (float)xcol * (1.0f / 121.0f);
        pyv = (float)(y0 + ro2) * (1.0f / 121.0f);
    }
    __syncthreads();

    // ---- phase B: butterfly-reduce 12 values (S, e*px, e*py per q) ----
    {
        float v[12] = {e0, e1, e2, e3,
                       e0 * pxv, e1 * pxv, e2 * pxv, e3 * pxv,
                       e0 * pyv, e1 * pyv, e2 * pyv, e3 * pyv};
        #pragma unroll
        for (int off = 32; off >= 1; off >>= 1)
            #pragma unroll
            for (int k = 0; k < 12; ++k) v[k] += __shfl_xor(v[k], off);
        if (lane == 0)
            #pragma unroll
            for (int k = 0; k < 12; ++k) sr12[w][k] = v[k];
    }

    // ---- phase C: smat partials (thread = (channel, stripe)) ----
    if (t < 240) {
        const int c = t % 40, j = t / 40;
        float a0 = 0, a1 = 0, a2s = 0, a3 = 0;
        for (int p = j; p < 244; p += 6) {
            const int prow = p + ((p >= 122) ? 6 : 0);
            float xv = bf2f(sxb[prow][c]);
            f32x4 ev = se4[p];
            a0 = fmaf(xv, ev[0], a0);
            a1 = fmaf(xv, ev[1], a1);
            a2s = fmaf(xv, ev[2], a2s);
            a3 = fmaf(xv, ev[3], a3);
        }
        ls[j][0][c] = a0; ls[j][1][c] = a1; ls[j][2][c] = a2s; ls[j][3][c] = a3;
    }

    // ---- coalesced x write from LDS (bf16-rounded) ----
    for (int i = t; i < 4880; i += 256) {
        const int run = i / 61, pp = i % 61;
        const int ro2 = run / 40, ch = run % 40;
        const int pos = pp * 2;
        const int srow = ro2 * 128 + pos;
        float va = bf2f(sxb[srow][ch]);
        float vb = bf2f(sxb[srow + 1][ch]);
        float* xp = x + ((size_t)b * C3 + ch) * HW3 + (size_t)(y0 + ro2) * W3 + pos;
        *(f32x2*)xp = (f32x2){va, vb};
    }
    __syncthreads();

    // ---- phase D: finalize block partials -> global atomics ----
    if (t < 160) {
        const int q = t / 40, c = t % 40;
        float s = ls[0][q][c] + ls[1][q][c] + ls[2][q][c] +
                  ls[3][q][c] + ls[4][q][c] + ls[5][q][c];
        atomicAdd(&smat_raw[(size_t)b * 160 + q * 40 + c], s);
    }
    if (t == 0) {
        #pragma unroll
        for (int k = 0; k < 4; ++k) {
            float sv = sr12[0][k] + sr12[1][k] + sr12[2][k] + sr12[3][k];
            atomicAdd(&S_raw[b * 4 + k], sv);
        }
        #pragma unroll
        for (int k = 0; k < 4; ++k) {
            float sx = sr12[0][4 + k] + sr12[1][4 + k] + sr12[2][4 + k] + sr12[3][4 + k];
            float sy = sr12[0][8 + k] + sr12[1][8 + k] + sr12[2][8 + k] + sr12[3][8 + k];
            atomicAdd(&pt_raw[b * 8 + k * 2], sx);
            atomicAdd(&pt_raw[b * 8 + k * 2 + 1], sy);
        }
    }
}

// ---------------- finish: inv = 1/S; pt_out, feat_out from raw sums ----------------
__global__ void k_finish(const float* __restrict__ S_raw, const float* __restrict__ pt_raw,
                         const float* __restrict__ smat_raw, const float* __restrict__ f_w,
                         float* __restrict__ pt_out, float* __restrict__ feat,
                         float* __restrict__ invS) {
    __shared__ float linv[4];
    const int b = blockIdx.x, t = threadIdx.x;
    if (t < 4) {
        float iv = 1.0f / S_raw[b * 4 + t];
        linv[t] = iv;
        invS[b * 4 + t] = iv;
    }
    __syncthreads();
    if (t < 40) {
        const int q = t / 10, d = t % 10;
        float s = 0.f;
        #pragma unroll
        for (int c = 0; c < 40; ++c)
            s = fmaf(f_w[(d * 4 + q) * 40 + c], smat_raw[(size_t)b * 160 + q * 40 + c], s);
        feat[b * 40 + t] = s * linv[q];
    }
    if (t < 8) pt_out[b * 8 + t] = pt_raw[b * 8 + t] * linv[t >> 1];
}

// ---------------- normalize att in place: att = e / S ----------------
__global__ __launch_bounds__(256) void k_attnorm(float* __restrict__ att,
                                                 const float* __restrict__ invS) {
    const int bq = blockIdx.y;
    const float iv = invS[bq];
    f32x4* a4 = (f32x4*)(att + (size_t)bq * HW3);
    constexpr int N4 = HW3 / 4;   // 3721
    for (int i = blockIdx.x * 256 + threadIdx.x; i < N4; i += 4 * 256) {
        f32x4 v = a4[i];
        v[0] *= iv; v[1] *= iv; v[2] *= iv; v[3] *= iv;
        a4[i] = v;
    }
}

// ---------------- launch ----------------
extern "C" void kernel_launch(void* const* d_in, const int* in_sizes, int n_in,
                              void* d_out, int out_size, void* d_ws, size_t ws_size,
                              hipStream_t stream) {
    const float* img   = (const float*)d_in[0];
    const float* w1    = (const float*)d_in[1];
    const float* b1    = (const float*)d_in[2];
    const float* w2    = (const float*)d_in[3];
    const float* b2    = (const float*)d_in[4];
    const float* w3    = (const float*)d_in[5];
    const float* b3    = (const float*)d_in[6];
    const float* k_w   = (const float*)d_in[7];
    const float* f_w   = (const float*)d_in[8];
    const float* query = (const float*)d_in[9];

    char* ws = (char*)d_ws;
    ushort* imgN = (ushort*)(ws + IMGN_B);
    ushort* a1   = (ushort*)(ws + A1_B);
    ushort* a2   = (ushort*)(ws + A2_B);
    ushort* bt1  = (ushort*)(ws + BT1_B);
    ushort* bt2  = (ushort*)(ws + BT2_B);
    ushort* bt3  = (ushort*)(ws + BT3_B);
    float*  qkw  = (float*)(ws + QKW_B);
    float*  smat_raw = (float*)(ws + SMATR_B);
    float*  S_raw    = (float*)(ws + SR_B);
    float*  pt_raw   = (float*)(ws + PTR_B);
    float*  invS     = (float*)(ws + INV_B);

    float* out  = (float*)d_out;
    float* x    = out;
    float* pt   = out + PT_OFF;
    float* feat = out + FEAT_OFF;
    float* att  = out + ATT_OFF;

    hipMemsetAsync(smat_raw, 0, RAW_SZB, stream);
    k_qkw<<<1, 256, 0, stream>>>(query, k_w, qkw);
    k_bt<<<80, 256, 0, stream>>>(w1, bt1, w2, bt2, w3, bt3);
    k_imgN<<<(BATCH * 16384) / 256, 256, 0, stream>>>(img, imgN);
    k_conv1_mfma<<<dim3(63, BATCH), 256, 0, stream>>>(imgN, bt1, b1, a1);
    k_conv2_mfma<<<dim3(62, BATCH), 256, 0, stream>>>(a1, bt2, b2, a2);
    k_conv3_mfma<<<dim3(61, BATCH), 256, 0, stream>>>(a2, bt3, b3, qkw, x, att,
                                                      smat_raw, S_raw, pt_raw);
    k_finish<<<BATCH, 64, 0, stream>>>(S_raw, pt_raw, smat_raw, f_w, pt, feat, invS);
    k_attnorm<<<dim3(4, BATCH * 4), 256, 0, stream>>>(att, invS);
}

// Round 7
// 399.202 us; speedup vs baseline: 1.0876x; 1.0334x over previous
//
#include <hip/hip_runtime.h>
#include <hip/hip_bf16.h>

// ---------------- problem constants ----------------
constexpr int BATCH = 64;
constexpr int H1 = 126, W1 = 126, C1 = 16;   // conv1 out
constexpr int H2 = 124, W2 = 124, C2 = 32;   // conv2 out
constexpr int H3 = 122, W3 = 122, C3 = 40;   // conv3 out (x)
constexpr int HW3 = H3 * W3;                 // 14884

typedef __attribute__((ext_vector_type(8))) short bf16x8;
typedef __attribute__((ext_vector_type(4))) float f32x4;
typedef __attribute__((ext_vector_type(2))) float f32x2;

__device__ __forceinline__ ushort f2bf(float f) {
    __hip_bfloat16 h = __float2bfloat16(f);
    return *reinterpret_cast<ushort*>(&h);
}
__device__ __forceinline__ float bf2f(ushort u) {
    return __uint_as_float((unsigned)u << 16);
}

// ---------------- ws layout (bytes) ----------------
constexpr size_t IMGN_B  = 0;                                    // bf16 NHWC8 (64,128,128,8)
constexpr size_t IMGN_SZ = (size_t)BATCH * 128 * 128 * 8 * 2;
constexpr size_t A1_B    = (IMGN_B + IMGN_SZ + 255) & ~(size_t)255;   // bf16 NHWC (64,126,126,16)
constexpr size_t A1_SZB  = (size_t)BATCH * H1 * W1 * C1 * 2;
constexpr size_t A2_B    = (A1_B + A1_SZB + 255) & ~(size_t)255;      // bf16 NHWC (64,124,124,32)
constexpr size_t A2_SZB  = (size_t)BATCH * H2 * W2 * C2 * 2;
constexpr size_t BT1_B   = (A2_B + A2_SZB + 255) & ~(size_t)255;      // bf16 [16][96]
constexpr size_t BT2_B   = (BT1_B + 16 * 96 * 2 + 255) & ~(size_t)255;   // bf16 [32][160]
constexpr size_t BT3_B   = (BT2_B + 32 * 160 * 2 + 255) & ~(size_t)255;  // bf16 [48][288]
constexpr size_t QKW_B   = (BT3_B + 48 * 288 * 2 + 255) & ~(size_t)255;  // f32 [160]
// raw attention accumulators (memset to 0 each launch)
constexpr size_t SMATR_B = (QKW_B + 160 * 4 + 255) & ~(size_t)255;
constexpr size_t SR_B    = SMATR_B + (size_t)BATCH * 160 * 4;
constexpr size_t PTR_B   = SR_B + (size_t)BATCH * 4 * 4;
constexpr size_t RAW_SZB = (size_t)BATCH * 160 * 4 + (size_t)BATCH * 4 * 4 + (size_t)BATCH * 8 * 4;
constexpr size_t INV_B   = (SMATR_B + RAW_SZB + 255) & ~(size_t)255;   // f32 [256]

// out layout (float elements)
constexpr size_t X_SZ     = (size_t)BATCH * C3 * HW3;
constexpr size_t PT_OFF   = X_SZ;
constexpr size_t FEAT_OFF = PT_OFF + BATCH * 8;
constexpr size_t ATT_OFF  = FEAT_OFF + BATCH * 40;

// ---------------- fold query into k_w; scale 1/122 ----------------
__global__ void k_qkw(const float* __restrict__ query, const float* __restrict__ k_w,
                      float* __restrict__ qkw) {
    int t = threadIdx.x;
    if (t < 160) {
        int q = t / 40, c = t % 40;
        float s = 0.f;
        #pragma unroll
        for (int d = 0; d < 10; ++d)
            s = fmaf(query[q * 10 + d], k_w[(d * 4 + q) * 40 + c], s);
        qkw[t] = s * (1.0f / 122.0f);
    }
}

// ---------------- weight transforms: Bt[n][k] bf16, zero-padded ----------------
__global__ void k_bt(const float* __restrict__ w1, ushort* __restrict__ bt1,
                     const float* __restrict__ w2, ushort* __restrict__ bt2,
                     const float* __restrict__ w3, ushort* __restrict__ bt3) {
    int t = blockIdx.x * 256 + threadIdx.x;
    if (t < 16 * 96) {
        int oc = t / 96, k = t % 96, cell = k >> 3, c = k & 7;
        float v = (c < 5 && cell < 9) ? w1[(oc * 5 + c) * 9 + cell] : 0.f;
        bt1[t] = f2bf(v);
    } else if (t < 16 * 96 + 32 * 160) {
        int u = t - 16 * 96;
        int n = u / 160, k = u % 160;
        float v = 0.f;
        if (k < 144) { int c = k & 15, cell = k >> 4; v = w2[(n * 16 + c) * 9 + cell]; }
        bt2[u] = f2bf(v);
    } else {
        int u = t - 16 * 96 - 32 * 160;
        if (u < 48 * 288) {
            int n = u / 288, k = u % 288;
            float v = 0.f;
            if (n < 40) { int c = k & 31, cell = k >> 5; v = w3[(n * 32 + c) * 9 + cell]; }
            bt3[u] = f2bf(v);
        }
    }
}

// ---------------- pack img + coords into NHWC8 bf16 ----------------
__global__ __launch_bounds__(256) void k_imgN(const float* __restrict__ img,
                                              ushort* __restrict__ imgN) {
    int tid = blockIdx.x * 256 + threadIdx.x;
    int b = tid >> 14, pix = tid & 16383;
    int y = pix >> 7, xc = pix & 127;
    const float* ip = img + (size_t)b * 3 * 16384 + pix;
    bf16x8 v;
    v[0] = (short)f2bf(ip[0]);
    v[1] = (short)f2bf(ip[16384]);
    v[2] = (short)f2bf(ip[32768]);
    v[3] = (short)f2bf(-1.0f + (2.0f / 127.0f) * (float)y);
    v[4] = (short)f2bf(-1.0f + (2.0f / 127.0f) * (float)xc);
    v[5] = 0; v[6] = 0; v[7] = 0;
    *(bf16x8*)(imgN + (size_t)tid * 8) = v;
}

// ---------------- conv1: implicit GEMM MFMA, 2 rows/block ----------------
__global__ __launch_bounds__(256) void k_conv1_mfma(const ushort* __restrict__ imgN,
                                                    const ushort* __restrict__ bt1,
                                                    const float* __restrict__ b1,
                                                    ushort* __restrict__ a1) {
    __shared__ ushort sx1[256][16];
    const int b = blockIdx.y, y0 = blockIdx.x * 2;
    const int t = threadIdx.x, lane = t & 63, w = t >> 6;
    const int col = lane & 15, g = lane >> 4;
    const int ro = w >> 1, xbase = (w & 1) * 64;

    f32x4 acc[4];
    const float bv = b1[col];
    #pragma unroll
    for (int mi = 0; mi < 4; ++mi) acc[mi] = (f32x4){bv, bv, bv, bv};

    #pragma unroll
    for (int ks = 0; ks < 3; ++ks) {
        bf16x8 bf = *(const bf16x8*)(bt1 + (size_t)col * 96 + ks * 32 + 8 * g);
        const int cell = ks * 4 + g;
        const bool valid = (cell < 9);
        const int ky = cell / 3, kx = cell % 3;
        #pragma unroll
        for (int mi = 0; mi < 4; ++mi) {
            const int xcol = xbase + mi * 16 + col;
            bf16x8 af = (bf16x8)0;
            if (valid) {
                const int row = y0 + ro + ky;
                const int xin = min(xcol + kx, 127);
                af = *(const bf16x8*)(imgN + (((size_t)b * 128 + row) * 128 + xin) * 8);
            }
            acc[mi] = __builtin_amdgcn_mfma_f32_16x16x32_bf16(af, bf, acc[mi], 0, 0, 0);
        }
    }

    #pragma unroll
    for (int mi = 0; mi < 4; ++mi) {
        const int m0 = w * 64 + mi * 16 + 4 * g;
        #pragma unroll
        for (int r = 0; r < 4; ++r)
            sx1[m0 + r][col] = f2bf(fmaxf(acc[mi][r], 0.0f));
    }
    __syncthreads();

    ushort* op = a1 + ((size_t)b * H1 + y0) * W1 * C1;
    for (int i = t; i < 504; i += 256) {
        int ro2 = i / 252, r = i % 252, xcol = r >> 1, c0 = (r & 1) * 8;
        *(bf16x8*)(op + ((size_t)ro2 * W1 + xcol) * C1 + c0) =
            *(const bf16x8*)(&sx1[ro2 * 128 + xcol][c0]);
    }
}

// ---------------- conv2: implicit GEMM MFMA, 2 rows/block ----------------
__global__ __launch_bounds__(256) void k_conv2_mfma(const ushort* __restrict__ a1,
                                                    const ushort* __restrict__ bt2,
                                                    const float* __restrict__ b2,
                                                    ushort* __restrict__ a2) {
    __shared__ ushort sx2[256][40];
    const int b = blockIdx.y, y0 = blockIdx.x * 2;
    const int t = threadIdx.x, lane = t & 63, w = t >> 6;
    const int col = lane & 15, g = lane >> 4;
    const int ro = w >> 1, xbase = (w & 1) * 64;

    f32x4 acc[4][2];
    #pragma unroll
    for (int mi = 0; mi < 4; ++mi)
        #pragma unroll
        for (int nf = 0; nf < 2; ++nf) {
            float bv = b2[nf * 16 + col];
            acc[mi][nf] = (f32x4){bv, bv, bv, bv};
        }

    #pragma unroll
    for (int ks = 0; ks < 5; ++ks) {
        bf16x8 bf[2];
        #pragma unroll
        for (int nf = 0; nf < 2; ++nf)
            bf[nf] = *(const bf16x8*)(bt2 + (size_t)(nf * 16 + col) * 160 + ks * 32 + 8 * g);
        const int cell = 2 * ks + (g >> 1);
        const bool valid = (cell <= 8);
        const int ky = cell / 3, kx = cell - ky * 3;
        const int c0 = 8 * (g & 1);
        #pragma unroll
        for (int mi = 0; mi < 4; ++mi) {
            const int xcol = xbase + mi * 16 + col;
            bf16x8 af = (bf16x8)0;
            if (valid) {
                const int row = y0 + ro + ky;
                const int xin = min(xcol + kx, W1 - 1);
                af = *(const bf16x8*)(a1 + (((size_t)b * H1 + row) * W1 + xin) * C1 + c0);
            }
            #pragma unroll
            for (int nf = 0; nf < 2; ++nf)
                acc[mi][nf] = __builtin_amdgcn_mfma_f32_16x16x32_bf16(af, bf[nf], acc[mi][nf], 0, 0, 0);
        }
    }

    #pragma unroll
    for (int mi = 0; mi < 4; ++mi) {
        const int m0 = w * 64 + mi * 16 + 4 * g;
        #pragma unroll
        for (int nf = 0; nf < 2; ++nf)
            #pragma unroll
            for (int r = 0; r < 4; ++r)
                sx2[m0 + r][nf * 16 + col] = f2bf(fmaxf(acc[mi][nf][r], 0.0f));
    }
    __syncthreads();

    ushort* op = a2 + ((size_t)b * H2 + y0) * W2 * C2;
    for (int i = t; i < 992; i += 256) {
        int ro2 = i / 496, r = i % 496, xcol = r >> 2, c0 = (r & 3) * 8;
        *(bf16x8*)(op + ((size_t)ro2 * W2 + xcol) * C2 + c0) =
            *(const bf16x8*)(&sx2[ro2 * 128 + xcol][c0]);
    }
}

// ---------------- conv3: implicit GEMM MFMA + fused scores/exp + attention reductions.
// x stored DIRECTLY from regs (overlapped f32x2 stores, round-5 pattern);
// bf16 LDS tile only for score dot + smat partials.
__global__ __launch_bounds__(256) void k_conv3_mfma(const ushort* __restrict__ a2,
                                                    const ushort* __restrict__ bt3,
                                                    const float* __restrict__ b3,
                                                    const float* __restrict__ qkw,
                                                    float* __restrict__ x,
                                                    float* __restrict__ att,
                                                    float* __restrict__ smat_raw,
                                                    float* __restrict__ S_raw,
                                                    float* __restrict__ pt_raw) {
    __shared__ ushort sxb[256][42];     // bf16 x tile, PAD=42 (odd dword stride)
    __shared__ f32x4 se4[244];          // e per position (4 q)
    __shared__ float ls[6][4][40];      // smat partials
    __shared__ float lq[160];
    __shared__ float sr12[4][12];       // per-wave S/pt partials
    const int b = blockIdx.y, y0 = blockIdx.x * 2;
    const int t = threadIdx.x, lane = t & 63, w = t >> 6;
    const int col = lane & 15, g = lane >> 4;
    const int ro = w >> 1, xbase = (w & 1) * 64;

    f32x4 acc[4][3];
    #pragma unroll
    for (int mi = 0; mi < 4; ++mi)
        #pragma unroll
        for (int nf = 0; nf < 3; ++nf) {
            const int ch = nf * 16 + col;
            float bv = (ch < 40) ? b3[ch] : 0.f;
            acc[mi][nf] = (f32x4){bv, bv, bv, bv};
        }

    #pragma unroll
    for (int ky = 0; ky < 3; ++ky) {
        #pragma unroll
        for (int kx = 0; kx < 3; ++kx) {
            const int ks = ky * 3 + kx;
            bf16x8 bf[3];
            #pragma unroll
            for (int nf = 0; nf < 3; ++nf)
                bf[nf] = *(const bf16x8*)(bt3 + (size_t)(nf * 16 + col) * 288 + ks * 32 + 8 * g);
            const ushort* arow = a2 + ((size_t)b * H2 + (y0 + ro + ky)) * W2 * C2;
            #pragma unroll
            for (int mi = 0; mi < 4; ++mi) {
                const int xcol = xbase + mi * 16 + col;
                const int xin = min(xcol + kx, W2 - 1);
                bf16x8 af = *(const bf16x8*)(arow + (size_t)xin * C2 + 8 * g);
                #pragma unroll
                for (int nf = 0; nf < 3; ++nf)
                    acc[mi][nf] = __builtin_amdgcn_mfma_f32_16x16x32_bf16(af, bf[nf], acc[mi][nf], 0, 0, 0);
            }
        }
    }

    for (int i = t; i < 160; i += 256) lq[i] = qkw[i];

    // ReLU; stage bf16 to LDS; DIRECT overlapped f32 x stores from registers
    #pragma unroll
    for (int mi = 0; mi < 4; ++mi) {
        const int m0 = w * 64 + mi * 16 + 4 * g;
        const int ro2 = m0 >> 7, xc0 = m0 & 127;
        const int row = y0 + ro2;
        #pragma unroll
        for (int nf = 0; nf < 3; ++nf) {
            const int ch = nf * 16 + col;
            if (ch < 40) {
                f32x4 v;
                #pragma unroll
                for (int r = 0; r < 4; ++r) v[r] = fmaxf(acc[mi][nf][r], 0.0f);
                #pragma unroll
                for (int r = 0; r < 4; ++r) sxb[m0 + r][ch] = f2bf(v[r]);
                if (xc0 < 120) {
                    float* xp = x + ((size_t)b * C3 + ch) * HW3 + (size_t)row * W3 + xc0;
                    *(f32x2*)xp       = (f32x2){v[0], v[1]};
                    *(f32x2*)(xp + 2) = (f32x2){v[2], v[3]};
                } else if (xc0 == 120) {
                    float* xp = x + ((size_t)b * C3 + ch) * HW3 + (size_t)row * W3 + xc0;
                    *(f32x2*)xp = (f32x2){v[0], v[1]};
                }
            }
        }
    }
    __syncthreads();

    // ---- phase A: scores -> e = exp(s); write att_raw; stage e ----
    float e0 = 0, e1 = 0, e2 = 0, e3 = 0, pxv = 0, pyv = 0;
    if (t < 244) {
        const int ro2 = (t >= 122) ? 1 : 0;
        const int xcol = t - ro2 * 122;
        const int srow = ro2 * 128 + xcol;
        const ushort* rowp = &sxb[srow][0];
        float s0 = 0, s1 = 0, s2 = 0, s3 = 0;
        #pragma unroll
        for (int k = 0; k < 10; ++k) {
            uint ua = *(const uint*)(rowp + 4 * k);
            uint ub = *(const uint*)(rowp + 4 * k + 2);
            float v0 = bf2f((ushort)(ua & 0xffff));
            float v1 = bf2f((ushort)(ua >> 16));
            float v2 = bf2f((ushort)(ub & 0xffff));
            float v3 = bf2f((ushort)(ub >> 16));
            const int c = 4 * k;
            s0 = fmaf(v0, lq[c], fmaf(v1, lq[c + 1], fmaf(v2, lq[c + 2], fmaf(v3, lq[c + 3], s0))));
            s1 = fmaf(v0, lq[40 + c], fmaf(v1, lq[41 + c], fmaf(v2, lq[42 + c], fmaf(v3, lq[43 + c], s1))));
            s2 = fmaf(v0, lq[80 + c], fmaf(v1, lq[81 + c], fmaf(v2, lq[82 + c], fmaf(v3, lq[83 + c], s2))));
            s3 = fmaf(v0, lq[120 + c], fmaf(v1, lq[121 + c], fmaf(v2, lq[122 + c], fmaf(v3, lq[123 + c], s3))));
        }
        e0 = __expf(s0); e1 = __expf(s1); e2 = __expf(s2); e3 = __expf(s3);
        const int p = (y0 + ro2) * W3 + xcol;
        float* ap = att + (size_t)b * 4 * HW3 + p;
        ap[0] = e0; ap[HW3] = e1; ap[2 * HW3] = e2; ap[3 * HW3] = e3;
        se4[t] = (f32x4){e0, e1, e2, e3};
        pxv = (float)xcol * (1.0f / 121.0f);
        pyv = (float)(y0 + ro2) * (1.0f / 121.0f);
    }

    // ---- phase B: butterfly-reduce 12 values (S, e*px, e*py per q) ----
    {
        float v[12] = {e0, e1, e2, e3,
                       e0 * pxv, e1 * pxv, e2 * pxv, e3 * pxv,
                       e0 * pyv, e1 * pyv, e2 * pyv, e3 * pyv};
        #pragma unroll
        for (int off = 32; off >= 1; off >>= 1)
            #pragma unroll
            for (int k = 0; k < 12; ++k) v[k] += __shfl_xor(v[k], off);
        if (lane == 0)
            #pragma unroll
            for (int k = 0; k < 12; ++k) sr12[w][k] = v[k];
    }
    __syncthreads();

    // ---- phase C: smat partials (thread = (channel, stripe)) ----
    if (t < 240) {
        const int c = t % 40, j = t / 40;
        float a0 = 0, a1 = 0, a2s = 0, a3 = 0;
        for (int p = j; p < 244; p += 6) {
            const int prow = p + ((p >= 122) ? 6 : 0);
            float xv = bf2f(sxb[prow][c]);
            f32x4 ev = se4[p];
            a0 = fmaf(xv, ev[0], a0);
            a1 = fmaf(xv, ev[1], a1);
            a2s = fmaf(xv, ev[2], a2s);
            a3 = fmaf(xv, ev[3], a3);
        }
        ls[j][0][c] = a0; ls[j][1][c] = a1; ls[j][2][c] = a2s; ls[j][3][c] = a3;
    }
    __syncthreads();

    // ---- phase D: finalize block partials -> global atomics ----
    if (t < 160) {
        const int q = t / 40, c = t % 40;
        float s = ls[0][q][c] + ls[1][q][c] + ls[2][q][c] +
                  ls[3][q][c] + ls[4][q][c] + ls[5][q][c];
        atomicAdd(&smat_raw[(size_t)b * 160 + q * 40 + c], s);
    }
    if (t == 0) {
        #pragma unroll
        for (int k = 0; k < 4; ++k) {
            float sv = sr12[0][k] + sr12[1][k] + sr12[2][k] + sr12[3][k];
            atomicAdd(&S_raw[b * 4 + k], sv);
        }
        #pragma unroll
        for (int k = 0; k < 4; ++k) {
            float sx = sr12[0][4 + k] + sr12[1][4 + k] + sr12[2][4 + k] + sr12[3][4 + k];
            float sy = sr12[0][8 + k] + sr12[1][8 + k] + sr12[2][8 + k] + sr12[3][8 + k];
            atomicAdd(&pt_raw[b * 8 + k * 2], sx);
            atomicAdd(&pt_raw[b * 8 + k * 2 + 1], sy);
        }
    }
}

// ---------------- finish: inv = 1/S; pt_out, feat_out from raw sums ----------------
__global__ void k_finish(const float* __restrict__ S_raw, const float* __restrict__ pt_raw,
                         const float* __restrict__ smat_raw, const float* __restrict__ f_w,
                         float* __restrict__ pt_out, float* __restrict__ feat,
                         float* __restrict__ invS) {
    __shared__ float linv[4];
    const int b = blockIdx.x, t = threadIdx.x;
    if (t < 4) {
        float iv = 1.0f / S_raw[b * 4 + t];
        linv[t] = iv;
        invS[b * 4 + t] = iv;
    }
    __syncthreads();
    if (t < 40) {
        const int q = t / 10, d = t % 10;
        float s = 0.f;
        #pragma unroll
        for (int c = 0; c < 40; ++c)
            s = fmaf(f_w[(d * 4 + q) * 40 + c], smat_raw[(size_t)b * 160 + q * 40 + c], s);
        feat[b * 40 + t] = s * linv[q];
    }
    if (t < 8) pt_out[b * 8 + t] = pt_raw[b * 8 + t] * linv[t >> 1];
}

// ---------------- normalize att in place: att = e / S ----------------
__global__ __launch_bounds__(256) void k_attnorm(float* __restrict__ att,
                                                 const float* __restrict__ invS) {
    const int bq = blockIdx.y;
    const float iv = invS[bq];
    f32x4* a4 = (f32x4*)(att + (size_t)bq * HW3);
    constexpr int N4 = HW3 / 4;   // 3721
    for (int i = blockIdx.x * 256 + threadIdx.x; i < N4; i += 4 * 256) {
        f32x4 v = a4[i];
        v[0] *= iv; v[1] *= iv; v[2] *= iv; v[3] *= iv;
        a4[i] = v;
    }
}

// ---------------- launch ----------------
extern "C" void kernel_launch(void* const* d_in, const int* in_sizes, int n_in,
                              void* d_out, int out_size, void* d_ws, size_t ws_size,
                              hipStream_t stream) {
    const float* img   = (const float*)d_in[0];
    const float* w1    = (const float*)d_in[1];
    const float* b1    = (const float*)d_in[2];
    const float* w2    = (const float*)d_in[3];
    const float* b2    = (const float*)d_in[4];
    const float* w3    = (const float*)d_in[5];
    const float* b3    = (const float*)d_in[6];
    const float* k_w   = (const float*)d_in[7];
    const float* f_w   = (const float*)d_in[8];
    const float* query = (const float*)d_in[9];

    char* ws = (char*)d_ws;
    ushort* imgN = (ushort*)(ws + IMGN_B);
    ushort* a1   = (ushort*)(ws + A1_B);
    ushort* a2   = (ushort*)(ws + A2_B);
    ushort* bt1  = (ushort*)(ws + BT1_B);
    ushort* bt2  = (ushort*)(ws + BT2_B);
    ushort* bt3  = (ushort*)(ws + BT3_B);
    float*  qkw  = (float*)(ws + QKW_B);
    float*  smat_raw = (float*)(ws + SMATR_B);
    float*  S_raw    = (float*)(ws + SR_B);
    float*  pt_raw   = (float*)(ws + PTR_B);
    float*  invS     = (float*)(ws + INV_B);

    float* out  = (float*)d_out;
    float* x    = out;
    float* pt   = out + PT_OFF;
    float* feat = out + FEAT_OFF;
    float* att  = out + ATT_OFF;

    hipMemsetAsync(smat_raw, 0, RAW_SZB, stream);
    k_qkw<<<1, 256, 0, stream>>>(query, k_w, qkw);
    k_bt<<<80, 256, 0, stream>>>(w1, bt1, w2, bt2, w3, bt3);
    k_imgN<<<(BATCH * 16384) / 256, 256, 0, stream>>>(img, imgN);
    k_conv1_mfma<<<dim3(63, BATCH), 256, 0, stream>>>(imgN, bt1, b1, a1);
    k_conv2_mfma<<<dim3(62, BATCH), 256, 0, stream>>>(a1, bt2, b2, a2);
    k_conv3_mfma<<<dim3(61, BATCH), 256, 0, stream>>>(a2, bt3, b3, qkw, x, att,
                                                      smat_raw, S_raw, pt_raw);
    k_finish<<<BATCH, 64, 0, stream>>>(S_raw, pt_raw, smat_raw, f_w, pt, feat, invS);
    k_attnorm<<<dim3(4, BATCH * 4), 256, 0, stream>>>(att, invS);
}